// Round 9
// baseline (69.656 us; speedup 1.0000x reference)
//
#include <hip/hip_runtime.h>

// Problem constants
#define B 4
#define S 8192
#define D 256
#define H 8
#define LOG2E 1.4426950408889634f
#define E2(x) __builtin_amdgcn_exp2f(x)

// Workspace layout (float offsets)
#define WS_WQ    0                       // 8 final wq sums
#define WS_WV    8                       // 8 final wv sums
#define WS_CV    16                      // B*D
#define WS_KC    (WS_CV + B*D)           // B*H*D
#define WS_WP    (WS_KC + B*H*D)         // 1024 weight partials
#define WS_P3    (WS_WP + 1024)          // B*128*D v-sum partials
#define WS_QMAXC (WS_P3 + B*128*D)       // B*256*D chunk q-max
#define WS_QMINC (WS_QMAXC + B*256*D)    // B*256*D chunk q-min
#define WS_ZC    (WS_QMINC + B*256*D)    // B*256*H*D chunk Z partials (~8.4 MB)

// In-block reduce of the 1024 weight partials -> wsum[16] ((which,h) order).
// Partial layout (written by kP): o = which*8+h owns 64 consecutive floats.
__device__ __forceinline__ void reduce_wp(const float* __restrict__ ws,
                                          float* wsum, int t) {
    const int o = t >> 4, j = t & 15;
    const float* wp = ws + WS_WP + o * 64;
    float s = (wp[j] + wp[16 + j]) + (wp[32 + j] + wp[48 + j]);
    #pragma unroll
    for (int st = 1; st < 16; st <<= 1) s += __shfl_xor(s, st, 16);
    if (j == 0) wsum[o] = s;
    __syncthreads();
}

// ---------------------------------------------------------------------------
// kP: blocks [0,512): per-64-row-chunk col sums of v. [512,768): weight chunks.
__global__ __launch_bounds__(256) void kP(const float* __restrict__ v,
                                          const float* __restrict__ qw,
                                          const float* __restrict__ vw,
                                          float* __restrict__ ws) {
    const int blk = blockIdx.x;
    const int t = threadIdx.x, w = t >> 6, lane = t & 63;

    if (blk >= 512) {                          // weight partials
        const int i = blk - 512;               // which=i>>7, h=(i>>4)&7, ch=i&15
        const float4* src = (const float4*)(((i >> 7) ? vw : qw)
                              + (size_t)((i >> 4) & 7) * D * D) + (i & 15) * 1024;
        float sm = 0.f;
        #pragma unroll
        for (int j = 0; j < 4; ++j) {
            float4 a4 = src[j * 256 + t];
            sm += (a4.x + a4.y) + (a4.z + a4.w);
        }
        #pragma unroll
        for (int off = 32; off; off >>= 1) sm += __shfl_down(sm, off, 64);
        // o = which*8+h = i>>4; chunk slot = (i&15)*4 + w  -> o*64 + slot
        if (lane == 0) ws[WS_WP + (i >> 4) * 64 + (i & 15) * 4 + w] = sm;
        return;
    }

    const int b = blk >> 7, tl = blk & 127;
    const int g = lane >> 4, cl = lane & 15;
    const int cblk = w * 16 + cl;              // 16B col block, 0..63
    const float4* vbase = (const float4*)(v + ((size_t)b * S + tl * 64) * D);
    float4 vs = make_float4(0.f, 0.f, 0.f, 0.f);
    #pragma unroll 4
    for (int i = 0; i < 16; ++i) {
        float4 b4 = vbase[(i * 4 + g) * 64 + cblk];
        vs.x += b4.x; vs.y += b4.y; vs.z += b4.z; vs.w += b4.w;
    }
    #pragma unroll
    for (int off = 16; off <= 32; off <<= 1) {
        vs.x += __shfl_xor(vs.x, off, 64);
        vs.y += __shfl_xor(vs.y, off, 64);
        vs.z += __shfl_xor(vs.z, off, 64);
        vs.w += __shfl_xor(vs.w, off, 64);
    }
    if (g == 0)
        *(float4*)&ws[WS_P3 + (size_t)(b * 128 + tl) * D + cblk * 4] = vs;
}

// ---------------------------------------------------------------------------
// kZ: single q pass. 1024 blocks = (b, 32-row chunk). Thread = column d;
// 32 rows held in registers -> chunk-local max/min AND chunk-local-referenced
// Z[h] in one pass. No atomics, no global-stats dependency.
__global__ __launch_bounds__(256) void kZ(const float* __restrict__ q,
                                          float* __restrict__ ws) {
    __shared__ float wsum[16];
    reduce_wp(ws, wsum, threadIdx.x);

    const int blk = blockIdx.x;
    const int b = blk >> 8, c = blk & 255;
    const int d = threadIdx.x;
    const float* qp = q + ((size_t)b * S + (size_t)c * 32) * D + d;

    float qv[32];
    #pragma unroll
    for (int r = 0; r < 32; ++r) qv[r] = qp[(size_t)r * D];

    float mx = qv[0], mn = qv[0];
    #pragma unroll
    for (int r = 1; r < 32; ++r) {
        mx = fmaxf(mx, qv[r]);
        mn = fminf(mn, qv[r]);
    }
    ws[WS_QMAXC + (size_t)(b * 256 + c) * D + d] = mx;
    ws[WS_QMINC + (size_t)(b * 256 + c) * D + d] = mn;

    float A[H], cc[H], z[H];
    #pragma unroll
    for (int h = 0; h < H; ++h) {
        A[h] = wsum[h] * LOG2E;
        cc[h] = -((A[h] >= 0.f) ? A[h] * mx : A[h] * mn);  // -max_r A*q
        z[h] = 0.f;
    }
    #pragma unroll
    for (int r = 0; r < 32; ++r) {
        #pragma unroll
        for (int h = 0; h < H; ++h) z[h] += E2(fmaf(qv[r], A[h], cc[h]));
    }
    const size_t zb = WS_ZC + ((size_t)(b * 256 + c) * H) * D + d;
    #pragma unroll
    for (int h = 0; h < H; ++h) ws[zb + h * D] = z[h];
}

// ---------------------------------------------------------------------------
// kM: blocks 0-31 (b,h): online-softmax merge of 256 chunk partials -> kc.
//     blocks 32-63: Cv merge. block 64: finalize wq/wv.
__global__ __launch_bounds__(256) void kM(float* __restrict__ ws) {
    __shared__ float wsum[16];
    reduce_wp(ws, wsum, threadIdx.x);
    const int blk = blockIdx.x, t = threadIdx.x;

    if (blk < 32) {
        const int b = blk >> 3, h = blk & 7;
        const float A = wsum[h] * LOG2E;
        float Mrun = -3.4e38f, Zrun = 0.f;
        #pragma unroll 4
        for (int c = 0; c < 256; ++c) {
            const float mxc = ws[WS_QMAXC + (size_t)(b * 256 + c) * D + t];
            const float mnc = ws[WS_QMINC + (size_t)(b * 256 + c) * D + t];
            const float zc  = ws[WS_ZC + ((size_t)(b * 256 + c) * H + h) * D + t];
            const float Mc = (A >= 0.f) ? A * mxc : A * mnc;
            const float nM = fmaxf(Mrun, Mc);
            Zrun = Zrun * E2(Mrun - nM) + zc * E2(Mc - nM);
            Mrun = nM;
        }
        ws[WS_KC + (size_t)(b * H + h) * D + t] =
            -Mrun - __builtin_amdgcn_logf(Zrun);   // v_log_f32 = log2
    } else if (blk < 64) {
        const int bb = (blk - 32) >> 3, oct = (blk - 32) & 7;
        const int dl = t >> 3, sub = t & 7;
        const int d = oct * 32 + dl;
        float sm = 0.f;
        #pragma unroll 4
        for (int i = 0; i < 16; ++i)
            sm += ws[WS_P3 + (size_t)(bb * 128 + sub * 16 + i) * D + d];
        #pragma unroll
        for (int off = 1; off < 8; off <<= 1) sm += __shfl_xor(sm, off, 64);
        if (sub == 0) ws[WS_CV + bb * D + d] = sm * (float)D;
    } else {
        if (t < 16) ws[(t >= 8) ? (WS_WV + t - 8) : (WS_WQ + t)] = wsum[t];
    }
}

// ---------------------------------------------------------------------------
// kE: 2048 blocks x 16 rows (8 blocks/CU). Thread = (row r = t>>4, slice =
// t&15). q straight from global (1KB-contiguous per 16 lanes); kc in LDS,
// swizzled [h][j][slice] for aligned conflict-free float4 reads; 4-step
// shfl_xor(16) reduce; wave-contiguous 1KB stores. (Proven R8 structure.)
__global__ __launch_bounds__(256) void kE(const float* __restrict__ q,
                                          const float* __restrict__ ws,
                                          float* __restrict__ out) {
    __shared__ float kcs[H * D];          // [h][j][slice][c] = h*256+j*64+slice*4+c
    __shared__ float ab2[16 * 2];

    const int blk = blockIdx.x;           // 2048 = B * 512
    const int b = blk >> 9, tl = blk & 511;
    const int t = threadIdx.x, w = t >> 6, lane = t & 63;
    const int r = t >> 4, slice = t & 15;

    // issue q loads first; HBM latency hides under the kc prologue
    const float4* qp = (const float4*)(q + ((size_t)b * S + tl * 16 + r) * D
                                       + slice * 16);
    const float4 q0 = qp[0], q1 = qp[1], q2 = qp[2], q3 = qp[3];

    // kc -> swizzled LDS (d = t: slice=d>>4, j=(d>>2)&3, c=d&3)
    const int dst = ((t >> 2) & 3) * 64 + (t >> 4) * 4 + (t & 3);
    #pragma unroll
    for (int h = 0; h < H; ++h)
        kcs[h * 256 + dst] = ws[WS_KC + (size_t)(b * H + h) * D + t];

    float a[H], wv_[H];
    #pragma unroll
    for (int h = 0; h < H; ++h) {
        a[h] = ws[WS_WQ + h] * LOG2E;
        wv_[h] = ws[WS_WV + h];
    }
    const float4 cv4 = *(const float4*)&ws[WS_CV + b * D + lane * 4];
    __syncthreads();

    float p[H];
    #pragma unroll
    for (int h = 0; h < H; ++h) p[h] = 0.f;

    const float4* kc4 = (const float4*)kcs;
    #pragma unroll
    for (int j = 0; j < 4; ++j) {
        const float4 qv = (j == 0) ? q0 : (j == 1) ? q1 : (j == 2) ? q2 : q3;
        #pragma unroll
        for (int h = 0; h < H; ++h) {
            const float4 k = kc4[h * 64 + j * 16 + slice];
            p[h] += (E2(fmaf(qv.x, a[h], k.x)) + E2(fmaf(qv.y, a[h], k.y)))
                  + (E2(fmaf(qv.z, a[h], k.z)) + E2(fmaf(qv.w, a[h], k.w)));
        }
    }
    #pragma unroll
    for (int st = 1; st < 16; st <<= 1) {
        #pragma unroll
        for (int h = 0; h < H; ++h) p[h] += __shfl_xor(p[h], st, 16);
    }
    float amax = -3.4e38f, amin = 3.4e38f;
    #pragma unroll
    for (int h = 0; h < H; ++h) {
        const float A = wv_[h] * p[h];
        amax = fmaxf(amax, A);
        amin = fminf(amin, A);
    }
    if (slice == 0) {
        ab2[r * 2] = amax;
        ab2[r * 2 + 1] = amin;
    }
    __syncthreads();

    float* og = out + ((size_t)b * S + tl * 16 + w * 4) * D;
    #pragma unroll
    for (int rr = 0; rr < 4; ++rr) {
        const float am = ab2[(w * 4 + rr) * 2];       // uniform broadcast
        const float an = ab2[(w * 4 + rr) * 2 + 1];
        float4 o;
        o.x = (cv4.x >= 0.f) ? cv4.x * am : cv4.x * an;
        o.y = (cv4.y >= 0.f) ? cv4.y * am : cv4.y * an;
        o.z = (cv4.z >= 0.f) ? cv4.z * am : cv4.z * an;
        o.w = (cv4.w >= 0.f) ? cv4.w * am : cv4.w * an;
        *(float4*)&og[(size_t)rr * D + lane * 4] = o;  // 1KB/wave contiguous
    }
}

// ---------------------------------------------------------------------------
extern "C" void kernel_launch(void* const* d_in, const int* in_sizes, int n_in,
                              void* d_out, int out_size, void* d_ws, size_t ws_size,
                              hipStream_t stream) {
    const float* q  = (const float*)d_in[0];
    // d_in[1] (k) and d_in[4] (k_weights) are provably unused: softmax over s sums to 1.
    const float* v  = (const float*)d_in[2];
    const float* qw = (const float*)d_in[3];
    const float* vw = (const float*)d_in[5];
    float* out = (float*)d_out;
    float* ws  = (float*)d_ws;

    kP<<<768, 256, 0, stream>>>(v, qw, vw, ws);
    kZ<<<B * 256, 256, 0, stream>>>(q, ws);
    kM<<<65, 256, 0, stream>>>(ws);
    kE<<<B * 512, 256, 0, stream>>>(q, ws, out);
}

// Round 10
// 51.498 us; speedup vs baseline: 1.3526x; 1.3526x over previous
//
#include <hip/hip_runtime.h>

// Problem constants
#define B 4
#define S 8192
#define D 256
#define H 8
#define NT 128               // col-stat tiles per batch (kA), 64 rows each
#define LOG2E 1.4426950408889634f
#define E2(x) __builtin_amdgcn_exp2f(x)

// Workspace layout (float offsets)
#define WS_WQ    0
#define WS_WV    8
#define WS_QMAX  16
#define WS_QMIN  (WS_QMAX + B*D)
#define WS_CV    (WS_QMIN + B*D)
#define WS_ZACC  (WS_CV + B*D)          // B*H*D
#define WS_WP    (WS_ZACC + B*H*D)      // 1024 weight partials
#define WS_P1    (WS_WP + 1024)
#define WS_P2    (WS_P1 + B*NT*D)
#define WS_P3    (WS_P2 + B*NT*D)

// ---------------------------------------------------------------------------
// kA: blocks [0,512): per-tile col stats of q (max/min) and v (sum).
//     blocks [512,768): weight-chunk partial sums.
__global__ __launch_bounds__(256) void kA(const float* __restrict__ q,
                                          const float* __restrict__ v,
                                          const float* __restrict__ qw,
                                          const float* __restrict__ vw,
                                          float* __restrict__ ws) {
    const int blk = blockIdx.x;
    const int t = threadIdx.x, w = t >> 6, lane = t & 63;

    if (blk >= B * NT) {                       // weight partials
        const int i = blk - B * NT;            // 0..255: which=i>>7, h=(i>>4)&7, ch=i&15
        const float4* src = (const float4*)(((i >> 7) ? vw : qw)
                              + (size_t)((i >> 4) & 7) * D * D) + (i & 15) * 1024;
        float sm = 0.f;
        #pragma unroll
        for (int j = 0; j < 4; ++j) {
            float4 a4 = src[j * 256 + t];
            sm += (a4.x + a4.y) + (a4.z + a4.w);
        }
        #pragma unroll
        for (int off = 32; off; off >>= 1) sm += __shfl_down(sm, off, 64);
        if (lane == 0) ws[WS_WP + i * 4 + w] = sm;
        return;
    }

    const int b = blk >> 7, tl = blk & (NT - 1);
    const int g = lane >> 4, cl = lane & 15;
    const int cblk = w * 16 + cl;              // 16B col block, 0..63
    const float4* qbase = (const float4*)(q + ((size_t)b * S + tl * 64) * D);
    const float4* vbase = (const float4*)(v + ((size_t)b * S + tl * 64) * D);
    float4 qmx = make_float4(-3.4e38f, -3.4e38f, -3.4e38f, -3.4e38f);
    float4 qmn = make_float4(3.4e38f, 3.4e38f, 3.4e38f, 3.4e38f);
    float4 vs = make_float4(0.f, 0.f, 0.f, 0.f);
    #pragma unroll 4
    for (int i = 0; i < 16; ++i) {
        const int row = i * 4 + g;
        float4 a4 = qbase[row * 64 + cblk];
        qmx.x = fmaxf(qmx.x, a4.x); qmx.y = fmaxf(qmx.y, a4.y);
        qmx.z = fmaxf(qmx.z, a4.z); qmx.w = fmaxf(qmx.w, a4.w);
        qmn.x = fminf(qmn.x, a4.x); qmn.y = fminf(qmn.y, a4.y);
        qmn.z = fminf(qmn.z, a4.z); qmn.w = fminf(qmn.w, a4.w);
        float4 b4 = vbase[row * 64 + cblk];
        vs.x += b4.x; vs.y += b4.y; vs.z += b4.z; vs.w += b4.w;
    }
    #pragma unroll
    for (int off = 16; off <= 32; off <<= 1) {
        qmx.x = fmaxf(qmx.x, __shfl_xor(qmx.x, off, 64));
        qmx.y = fmaxf(qmx.y, __shfl_xor(qmx.y, off, 64));
        qmx.z = fmaxf(qmx.z, __shfl_xor(qmx.z, off, 64));
        qmx.w = fmaxf(qmx.w, __shfl_xor(qmx.w, off, 64));
        qmn.x = fminf(qmn.x, __shfl_xor(qmn.x, off, 64));
        qmn.y = fminf(qmn.y, __shfl_xor(qmn.y, off, 64));
        qmn.z = fminf(qmn.z, __shfl_xor(qmn.z, off, 64));
        qmn.w = fminf(qmn.w, __shfl_xor(qmn.w, off, 64));
        vs.x += __shfl_xor(vs.x, off, 64);
        vs.y += __shfl_xor(vs.y, off, 64);
        vs.z += __shfl_xor(vs.z, off, 64);
        vs.w += __shfl_xor(vs.w, off, 64);
    }
    if (g == 0) {
        size_t pi = (size_t)(b * NT + tl) * D + cblk * 4;
        *(float4*)&ws[WS_P1 + pi] = qmx;
        *(float4*)&ws[WS_P2 + pi] = qmn;
        *(float4*)&ws[WS_P3 + pi] = vs;
    }
}

// ---------------------------------------------------------------------------
// kB: blocks 0..31 finish col stats; block 32 finishes weight sums;
//     block 33 zeroes the Z accumulators.
__global__ __launch_bounds__(256) void kB(float* __restrict__ ws) {
    const int blk = blockIdx.x, t = threadIdx.x;
    if (blk < 32) {
        const int bb = blk >> 3, oct = blk & 7;
        const int dl = t >> 3, sub = t & 7;
        const int d = oct * 32 + dl;
        float mx = -3.4e38f, mn = 3.4e38f, sm = 0.f;
        #pragma unroll 4
        for (int i = 0; i < 16; ++i) {
            size_t idx = (size_t)(bb * NT + sub * 16 + i) * D + d;
            mx = fmaxf(mx, ws[WS_P1 + idx]);
            mn = fminf(mn, ws[WS_P2 + idx]);
            sm += ws[WS_P3 + idx];
        }
        #pragma unroll
        for (int off = 1; off < 8; off <<= 1) {
            mx = fmaxf(mx, __shfl_xor(mx, off, 64));
            mn = fminf(mn, __shfl_xor(mn, off, 64));
            sm += __shfl_xor(sm, off, 64);
        }
        if (sub == 0) {
            ws[WS_QMAX + bb * D + d] = mx;
            ws[WS_QMIN + bb * D + d] = mn;
            ws[WS_CV + bb * D + d] = sm * (float)D;
        }
    } else if (blk == 32) {
        const int o = t >> 4, j = t & 15;        // o: 0..15 = (which,h)
        float s = 0.f;
        #pragma unroll
        for (int ww = 0; ww < 4; ++ww) s += ws[WS_WP + (o * 16 + j) * 4 + ww];
        #pragma unroll
        for (int off = 1; off < 16; off <<= 1) s += __shfl_xor(s, off, 16);
        if (j == 0) ws[(o >= 8) ? (WS_WV + o - 8) : (WS_WQ + o)] = s;
    } else {
        #pragma unroll
        for (int e = 0; e < 8; ++e)
            *(float4*)&ws[WS_ZACC + e * 1024 + t * 4] = make_float4(0.f, 0.f, 0.f, 0.f);
    }
}

// ---------------------------------------------------------------------------
// kC: Z partials over 64-row chunks (512 blocks -> 1M atomics, half of R8).
__global__ __launch_bounds__(256) void kC(const float* __restrict__ q,
                                          float* __restrict__ ws) {
    const int blk = blockIdx.x;          // 512 blocks: b = blk>>7, chunk = blk&127
    const int b = blk >> 7, c = blk & 127;
    const int d = threadIdx.x;
    const float qmx = ws[WS_QMAX + b * D + d];
    const float qmn = ws[WS_QMIN + b * D + d];
    float a[H], cc[H], z[H];
    #pragma unroll
    for (int h = 0; h < H; ++h) {
        float wq_ = ws[WS_WQ + h];
        float M = (wq_ >= 0.f) ? wq_ * qmx : wq_ * qmn;  // max_s of wq*q[b,s,d]
        a[h] = wq_ * LOG2E;
        cc[h] = -M * LOG2E;
        z[h] = 0.f;
    }
    const float* qp = q + ((size_t)b * S + c * 64) * D + d;
    #pragma unroll 4
    for (int r = 0; r < 64; ++r) {
        float qv = qp[(size_t)r * D];
        #pragma unroll
        for (int h = 0; h < H; ++h) z[h] += E2(fmaf(qv, a[h], cc[h]));
    }
    #pragma unroll
    for (int h = 0; h < H; ++h)
        atomicAdd(&ws[WS_ZACC + (size_t)(b * H + h) * D + d], z[h]);
}

// ---------------------------------------------------------------------------
// kE v6: 2048 blocks x 16 rows, __launch_bounds__(256,8) to force VGPR<=64
// (32 waves/CU). kc computed inline (kD fused) into swizzled LDS. Main loop:
// q from global (1KB-contiguous per 16 lanes), kc via aligned conflict-free
// float4 LDS reads, 4-step shfl_xor(16) reduce. Epilogue barrier-free:
// row-broadcast via __shfl within the owning wave; wv via uniform LDS read.
__global__ __launch_bounds__(256, 8) void kE(const float* __restrict__ q,
                                             const float* __restrict__ ws,
                                             float* __restrict__ out) {
    __shared__ float kcs[H * D];          // [h][j][slice][c] = h*256+j*64+slice*4+c
    __shared__ float wvs[8];

    const int blk = blockIdx.x;           // 2048 = B * 512
    const int b = blk >> 9, tl = blk & 511;
    const int t = threadIdx.x, w = t >> 6, lane = t & 63;
    const int r = t >> 4, slice = t & 15;

    // issue q loads first; HBM latency hides under the kc prologue
    const float4* qp = (const float4*)(q + ((size_t)b * S + tl * 16 + r) * D
                                       + slice * 16);
    const float4 q0 = qp[0], q1 = qp[1], q2 = qp[2], q3 = qp[3];

    // fused kD: kc[h][d=t] = -M*log2e - log2(Z); swizzled store
    const int dst = ((t >> 2) & 3) * 64 + (t >> 4) * 4 + (t & 3);
    const float qmx = ws[WS_QMAX + b * D + t];
    const float qmn = ws[WS_QMIN + b * D + t];
    float a[H];
    #pragma unroll
    for (int h = 0; h < H; ++h) {
        const float wq_ = ws[WS_WQ + h];
        const float M = (wq_ >= 0.f) ? wq_ * qmx : wq_ * qmn;
        kcs[h * 256 + dst] = -M * LOG2E
            - __builtin_amdgcn_logf(ws[WS_ZACC + (size_t)(b * H + h) * D + t]);
        a[h] = wq_ * LOG2E;
    }
    if (t < 8) wvs[t] = ws[WS_WV + t];
    const float4 cv4 = *(const float4*)&ws[WS_CV + b * D + lane * 4];
    __syncthreads();

    float p[H];
    #pragma unroll
    for (int h = 0; h < H; ++h) p[h] = 0.f;

    const float4* kc4 = (const float4*)kcs;
    #pragma unroll
    for (int j = 0; j < 4; ++j) {
        const float4 qv = (j == 0) ? q0 : (j == 1) ? q1 : (j == 2) ? q2 : q3;
        #pragma unroll
        for (int h = 0; h < H; ++h) {
            const float4 k = kc4[h * 64 + j * 16 + slice];
            p[h] += (E2(fmaf(qv.x, a[h], k.x)) + E2(fmaf(qv.y, a[h], k.y)))
                  + (E2(fmaf(qv.z, a[h], k.z)) + E2(fmaf(qv.w, a[h], k.w)));
        }
    }
    #pragma unroll
    for (int st = 1; st < 16; st <<= 1) {
        #pragma unroll
        for (int h = 0; h < H; ++h) p[h] += __shfl_xor(p[h], st, 16);
    }
    float amax = -3.4e38f, amin = 3.4e38f;
    #pragma unroll
    for (int h = 0; h < H; ++h) {
        const float A = wvs[h] * p[h];    // uniform LDS broadcast
        amax = fmaxf(amax, A);
        amin = fminf(amin, A);
    }

    // barrier-free epilogue: rows w*4+rr were reduced within this wave,
    // their amax/amin live (replicated) in lanes rr*16..rr*16+15.
    float* og = out + ((size_t)b * S + tl * 16 + w * 4) * D;
    #pragma unroll
    for (int rr = 0; rr < 4; ++rr) {
        const float am = __shfl(amax, rr * 16, 64);
        const float an = __shfl(amin, rr * 16, 64);
        float4 o;
        o.x = (cv4.x >= 0.f) ? cv4.x * am : cv4.x * an;
        o.y = (cv4.y >= 0.f) ? cv4.y * am : cv4.y * an;
        o.z = (cv4.z >= 0.f) ? cv4.z * am : cv4.z * an;
        o.w = (cv4.w >= 0.f) ? cv4.w * am : cv4.w * an;
        *(float4*)&og[(size_t)rr * D + lane * 4] = o;  // 1KB/wave contiguous
    }
}

// ---------------------------------------------------------------------------
extern "C" void kernel_launch(void* const* d_in, const int* in_sizes, int n_in,
                              void* d_out, int out_size, void* d_ws, size_t ws_size,
                              hipStream_t stream) {
    const float* q  = (const float*)d_in[0];
    // d_in[1] (k) and d_in[4] (k_weights) are provably unused: softmax over s sums to 1.
    const float* v  = (const float*)d_in[2];
    const float* qw = (const float*)d_in[3];
    const float* vw = (const float*)d_in[5];
    float* out = (float*)d_out;
    float* ws  = (float*)d_ws;

    kA<<<B * NT + 256, 256, 0, stream>>>(q, v, qw, vw, ws);
    kB<<<34, 256, 0, stream>>>(ws);
    kC<<<512, 256, 0, stream>>>(q, ws);
    kE<<<B * 512, 256, 0, stream>>>(q, ws, out);
}